// Round 8
// baseline (1470.282 us; speedup 1.0000x reference)
//
#include <hip/hip_runtime.h>
#include <stdint.h>

constexpr int B = 512, S = 1024, IN = 32, H = 128;
constexpr int KTOT = IN + H;    // 160
constexpr int NJ = 4;           // k-slices (wave-uniform)
constexpr int KSL = KTOT / NJ;  // 40 k per slice
constexpr int KP = KSL / 2;     // 20 half2 pairs

typedef uint32_t u32;

// D = a.h0*b.h0 + a.h1*b.h1 + D  (fp16 inputs, fp32 accumulate)
__device__ __forceinline__ void dot2(float& c, u32 a, u32 b) {
  asm("v_dot2_f32_f16 %0, %1, %2, %0" : "+v"(c) : "v"(a), "v"(b));
}
__device__ __forceinline__ float sigm(float v) {
  float e = __builtin_amdgcn_exp2f(-1.4426950408889634f * v);
  return __builtin_amdgcn_rcpf(1.0f + e);
}
__device__ __forceinline__ float tanh_(float v) {
  float e = __builtin_amdgcn_exp2f(-2.8853900817779268f * v);
  return 2.0f * __builtin_amdgcn_rcpf(1.0f + e) - 1.0f;
}

// 1024-thread block = 16 waves = 4 waves/SIMD from ONE block (no co-residency
// gamble). r7 lesson: allocator squeezed to 48 VGPR (8 free after 40 pinned
// weights) -> serialized LDS reads, ~1900cy exposed act latency. This round
// pin-fences the load groups to force concurrent liveness (~90 regs).
__global__ __launch_bounds__(1024, 1)
void lstm_fused(const float* __restrict__ x, const float* __restrict__ Wih,
                const float* __restrict__ Whh, const float* __restrict__ bih,
                const float* __restrict__ bhh, const float* __restrict__ Wlin,
                const float* __restrict__ blin, float* __restrict__ out) {
  __shared__ alignas(16) _Float16 hx0[2][KTOT];  // row0 ping-pong [x(32)|h(128)]
  __shared__ alignas(16) _Float16 hx1[2][KTOT];  // row1
  __shared__ float red0[NJ][H][5];  // stride-5 words: conflict-free act reads
  __shared__ float red1[NJ][H][5];
  __shared__ float redf[2][H];

  const int tid = threadIdx.x;
  const int lane = tid & 63;
  const int w = tid >> 6;             // wave 0..15
  const int j = w >> 2;               // k-slice 0..3 (wave-uniform)
  const int cp = (w >> 1) & 1;        // gate-pair: 0 -> {i,f}, 1 -> {g,o}
  const int g = (w & 1) * 64 + lane;  // gate-row 0..127
  const int r0 = blockIdx.x * 2;      // this block's two batch rows

  // one act wave per SIMD (w&3 = 0,1,2,3)
  const bool isact0 = (w == 0) || (w == 5);    // row0 act (P1 phase)
  const bool isact1 = (w == 10) || (w == 15);  // row1 act (P0 phase)
  const bool isact = isact0 || isact1;
  const int ga = ((w == 5) || (w == 15)) ? 64 + lane : lane;

  // ---- weights -> packed half2 regs: 2 gates x 20 pairs = 40 VGPRs ----
  u32 wreg[2][KP];
#pragma unroll
  for (int c2 = 0; c2 < 2; ++c2) {
    const int n = (2 * cp + c2) * H + g;
#pragma unroll
    for (int pq = 0; pq < KP; ++pq) {
      const int k0 = KSL * j + 2 * pq, k1 = k0 + 1;
      const float f0 = (k0 < IN) ? Wih[n * IN + k0] : Whh[n * H + (k0 - IN)];
      const float f1 = (k1 < IN) ? Wih[n * IN + k1] : Whh[n * H + (k1 - IN)];
      union { _Float16 h[2]; u32 u; } cv;
      cv.h[0] = (_Float16)f0;
      cv.h[1] = (_Float16)f1;
      wreg[c2][pq] = cv.u;
    }
  }
#pragma unroll
  for (int c2 = 0; c2 < 2; ++c2)
#pragma unroll
    for (int pq = 0; pq < KP; ++pq) asm volatile("" : "+v"(wreg[c2][pq]));

  float bias[4] = {0.f, 0.f, 0.f, 0.f};
  if (isact) {
#pragma unroll
    for (int c = 0; c < 4; ++c) bias[c] = bih[c * H + ga] + bhh[c * H + ga];
  }

  // ---- init: hx*[0] = (x_0 | zeros); hx*[1] zeroed ----
  const size_t xb0 = (size_t)r0 * S * IN, xb1 = (size_t)(r0 + 1) * S * IN;
  if (tid < KTOT) {
    hx0[0][tid] = (tid < IN) ? (_Float16)x[xb0 + tid] : (_Float16)0.0f;
    hx0[1][tid] = (_Float16)0.0f;
  } else if (tid < 2 * KTOT) {
    const int t = tid - KTOT;
    hx1[0][t] = (t < IN) ? (_Float16)x[xb1 + t] : (_Float16)0.0f;
    hx1[1][t] = (_Float16)0.0f;
  }
  __syncthreads();

  float cc = 0.f, oa = 0.f;

#define DOTS(HXROW, REDBUF)                                                  \
  {                                                                          \
    const uint4* pp = (const uint4*)&(HXROW)[0] + j * 5;                     \
    uint4 vv[5];                                                             \
    vv[0] = pp[0]; vv[1] = pp[1]; vv[2] = pp[2]; vv[3] = pp[3]; vv[4] = pp[4]; \
    asm volatile("" : "+v"(vv[0].x), "+v"(vv[0].y), "+v"(vv[0].z),           \
                      "+v"(vv[0].w), "+v"(vv[1].x), "+v"(vv[1].y),           \
                      "+v"(vv[1].z), "+v"(vv[1].w), "+v"(vv[2].x),           \
                      "+v"(vv[2].y), "+v"(vv[2].z), "+v"(vv[2].w),           \
                      "+v"(vv[3].x), "+v"(vv[3].y), "+v"(vv[3].z),           \
                      "+v"(vv[3].w), "+v"(vv[4].x), "+v"(vv[4].y),           \
                      "+v"(vv[4].z), "+v"(vv[4].w));                         \
    float a0 = 0.f, a1 = 0.f;                                                \
    _Pragma("unroll") for (int q = 0; q < 5; ++q) {                          \
      const u32 e[4] = {vv[q].x, vv[q].y, vv[q].z, vv[q].w};                 \
      _Pragma("unroll") for (int u = 0; u < 4; ++u) {                        \
        dot2(a0, e[u], wreg[0][4 * q + u]);                                  \
        dot2(a1, e[u], wreg[1][4 * q + u]);                                  \
      }                                                                      \
    }                                                                        \
    (REDBUF)[j][g][2 * cp] = a0;                                             \
    (REDBUF)[j][g][2 * cp + 1] = a1;                                         \
  }

#define ACT(REDBUF, HPTR, WL)                                                \
  {                                                                          \
    float r[16];                                                             \
    _Pragma("unroll") for (int jj = 0; jj < 4; ++jj)                         \
      _Pragma("unroll") for (int c = 0; c < 4; ++c)                          \
          r[4 * jj + c] = (REDBUF)[jj][ga][c];                               \
    asm volatile("" : "+v"(r[0]), "+v"(r[1]), "+v"(r[2]), "+v"(r[3]),        \
                      "+v"(r[4]), "+v"(r[5]), "+v"(r[6]), "+v"(r[7]),        \
                      "+v"(r[8]), "+v"(r[9]), "+v"(r[10]), "+v"(r[11]),      \
                      "+v"(r[12]), "+v"(r[13]), "+v"(r[14]), "+v"(r[15]));   \
    const float s0 = r[0] + r[4] + r[8] + r[12] + bias[0];                   \
    const float s1 = r[1] + r[5] + r[9] + r[13] + bias[1];                   \
    const float s2 = r[2] + r[6] + r[10] + r[14] + bias[2];                  \
    const float s3 = r[3] + r[7] + r[11] + r[15] + bias[3];                  \
    const float gi = sigm(s0), gf = sigm(s1);                                \
    const float gg = tanh_(s2), go = sigm(s3);                               \
    cc = gf * cc + gi * gg;                                                  \
    const float h = go * tanh_(cc);                                          \
    _Float16* hp = (HPTR);                                                   \
    if (hp) *hp = (_Float16)h;                                               \
    oa += h * (WL);                                                          \
  }

#define STEP(PB, SS)                                                         \
  {                                                                          \
    float wl = 0.f;                                                          \
    if (isact0) wl = Wlin[(SS)*H + ga];                                      \
    else if (isact1 && (SS) > 0) wl = Wlin[((SS)-1) * H + ga];               \
    /* P0: dots(row0,s) || act(row1,s-1) */                                  \
    DOTS(hx0[PB], red0);                                                     \
    if (isact1 && (SS) > 0) ACT(red1, &hx1[PB][IN + ga], wl);                \
    __syncthreads();                                                         \
    /* P1: dots(row1,s) || act(row0,s) || x prefetch */                      \
    DOTS(hx1[PB], red1);                                                     \
    if (isact0) ACT(red0, &hx0[PB ^ 1][IN + ga], wl);                        \
    if ((w == 2) && ((SS) + 1 < S)) {                                        \
      const int row = lane >> 5, k = lane & 31;                              \
      const float xv = x[(row ? xb1 : xb0) + (size_t)((SS) + 1) * IN + k];   \
      (row ? hx1 : hx0)[PB ^ 1][k] = (_Float16)xv;                           \
    }                                                                        \
    __syncthreads();                                                         \
  }

  for (int s = 0; s < S; s += 2) {
    STEP(0, s);
    STEP(1, s + 1);
  }

  // ---- epilogue: act(row1, S-1) (pipeline tail) ----
  if (isact1) {
    const float wlf = Wlin[(S - 1) * H + ga];
    ACT(red1, (_Float16*)0, wlf);
  }
  if (isact) redf[isact1 ? 1 : 0][ga] = oa;
  __syncthreads();
  if (tid < 2) {
    float sum = blin[0];
    for (int k = 0; k < H; ++k) sum += redf[tid][k];
    out[r0 + tid] = sum;
  }
#undef DOTS
#undef ACT
#undef STEP
}

extern "C" void kernel_launch(void* const* d_in, const int* in_sizes, int n_in,
                              void* d_out, int out_size, void* d_ws, size_t ws_size,
                              hipStream_t stream) {
  const float* x    = (const float*)d_in[0];
  const float* Wih  = (const float*)d_in[1];
  const float* Whh  = (const float*)d_in[2];
  const float* bih  = (const float*)d_in[3];
  const float* bhh  = (const float*)d_in[4];
  const float* Wlin = (const float*)d_in[5];
  const float* blin = (const float*)d_in[6];
  float* outp = (float*)d_out;
  hipLaunchKernelGGL(lstm_fused, dim3(B / 2), dim3(1024), 0, stream,
                     x, Wih, Whh, bih, bhh, Wlin, blin, outp);
}

// Round 10
// 1343.195 us; speedup vs baseline: 1.0946x; 1.0946x over previous
//
#include <hip/hip_runtime.h>
#include <stdint.h>

constexpr int B = 512, S = 1024, IN = 32, H = 128;
constexpr int CH = 32;  // prefetch chunk (steps)

typedef uint32_t u32;

template <int CTRL>
__device__ __forceinline__ float dpp_qp(float v) {
  return __int_as_float(__builtin_amdgcn_update_dpp(
      0, __float_as_int(v), CTRL, 0xF, 0xF, true));
}
// D = a.h0*b.h0 + a.h1*b.h1 + D  (fp16 inputs, fp32 accumulate)
__device__ __forceinline__ void dot2(float& c, u32 a, u32 b) {
  asm("v_dot2_f32_f16 %0, %1, %2, %0" : "+v"(c) : "v"(a), "v"(b));
}
__device__ __forceinline__ float sigm(float v) {
  float e = __builtin_amdgcn_exp2f(-1.4426950408889634f * v);
  return __builtin_amdgcn_rcpf(1.0f + e);
}
__device__ __forceinline__ float tanh_(float v) {
  float e = __builtin_amdgcn_exp2f(-2.8853900817779268f * v);
  return 2.0f * __builtin_amdgcn_rcpf(1.0f + e) - 1.0f;
}
__device__ __forceinline__ u32 pack2(float a, float b) {
  union { _Float16 h[2]; u32 u; } cv;
  cv.h[0] = (_Float16)a;
  cv.h[1] = (_Float16)b;
  return cv.u;
}

// SINGLE barrier per step; quad-DPP k-reduction (no red[] round-trip);
// NO global loads between barriers (32-step chunked prefetch of x and Wlin
// -> LDS; the only per-step vmem drain is once per 32 steps).
// launch_bounds (512,1): grid == 256 blocks == #CUs, so a 2nd block/CU is
// impossible anyway; the (512,2) 128-VGPR cap would only risk spilling the
// ~130-reg peak live set (r4/r5 spill lesson).
__global__ __launch_bounds__(512, 1)
void lstm_fused(const float* __restrict__ x, const float* __restrict__ Wih,
                const float* __restrict__ Whh, const float* __restrict__ bih,
                const float* __restrict__ bhh, const float* __restrict__ Wlin,
                const float* __restrict__ blin, float* __restrict__ out) {
  __shared__ alignas(16) _Float16 hxh[2][2][H];      // ping-pong h, 2 rows
  __shared__ alignas(16) u32 xc[2][CH][2][IN / 2];   // x chunks, half2
  __shared__ alignas(16) float wc[2][CH * H];        // Wlin chunks, fp32
  __shared__ float redf[2][H];

  const int tid = threadIdx.x;
  const int g = tid >> 2;  // hidden unit 0..127 (quad-uniform)
  const int j = tid & 3;   // k-slice within quad
  const int r0 = blockIdx.x * 2;
  const size_t xb0 = (size_t)r0 * S * IN, xb1 = xb0 + (size_t)S * IN;

  // ---- weights: per gate 4 x-pairs + 16 h-pairs = 20 u32; 4 gates = 80 ----
  u32 wr[4][20];
#pragma unroll
  for (int c = 0; c < 4; ++c) {
    const int n = c * H + g;
#pragma unroll
    for (int u = 0; u < 4; ++u)
      wr[c][u] = pack2(Wih[n * IN + 8 * j + 2 * u],
                       Wih[n * IN + 8 * j + 2 * u + 1]);
#pragma unroll
    for (int e = 0; e < 16; ++e)
      wr[c][4 + e] = pack2(Whh[n * H + 32 * j + 2 * e],
                           Whh[n * H + 32 * j + 2 * e + 1]);
  }
#pragma unroll
  for (int c = 0; c < 4; ++c)
#pragma unroll
    for (int e = 0; e < 20; ++e) asm volatile("" : "+v"(wr[c][e]));

  float bias[4];
#pragma unroll
  for (int c = 0; c < 4; ++c) bias[c] = bih[c * H + g] + bhh[c * H + g];

  // ---- init h = 0 ----
  if (tid < 2 * 2 * H / 2) ((u32*)hxh)[tid] = 0u;  // 256 u32 = all of hxh

  // ---- prologue: stage chunk 0 (x and Wlin) ----
  const int rw = tid >> 8, rem = tid & 255, so = rem >> 3, k4 = (rem & 7) * 4;
  {
    const float4 xv = *(const float4*)&x[(rw ? xb1 : xb0) + so * IN + k4];
    const float4 wv0 = *(const float4*)&Wlin[tid * 8];
    const float4 wv1 = *(const float4*)&Wlin[tid * 8 + 4];
    *(uint2*)&xc[0][so][rw][k4 >> 1] =
        make_uint2(pack2(xv.x, xv.y), pack2(xv.z, xv.w));
    *(float4*)&wc[0][tid * 8] = wv0;
    *(float4*)&wc[0][tid * 8 + 4] = wv1;
  }
  __syncthreads();

  float cc0 = 0.f, cc1 = 0.f, oa0 = 0.f, oa1 = 0.f;
  float4 pxv = make_float4(0, 0, 0, 0);
  float4 pwv0 = pxv, pwv1 = pxv;

  for (int s = 0; s < S; ++s) {
    const int t = s & (CH - 1), cb = (s >> 5) & 1, p = s & 1, np = p ^ 1;

    // chunk pipeline: issue loads at t==0 (drained at this step's barrier),
    // LDS-write them at t==1 (into the buffer not in use), consumed from t==32.
    if (t == 0 && s + CH < S) {
      pxv = *(const float4*)&x[(rw ? xb1 : xb0) + (size_t)(s + CH + so) * IN + k4];
      pwv0 = *(const float4*)&Wlin[(size_t)(s + CH) * H + tid * 8];
      pwv1 = *(const float4*)&Wlin[(size_t)(s + CH) * H + tid * 8 + 4];
    }
    if (t == 1 && s - 1 + CH < S) {
      *(uint2*)&xc[cb ^ 1][so][rw][k4 >> 1] =
          make_uint2(pack2(pxv.x, pxv.y), pack2(pxv.z, pxv.w));
      *(float4*)&wc[cb ^ 1][tid * 8] = pwv0;
      *(float4*)&wc[cb ^ 1][tid * 8 + 4] = pwv1;
    }

    // ---- dots: x from chunk, h from ping-pong; all broadcast b128 reads ----
    float a00 = 0.f, a10 = 0.f, a20 = 0.f, a30 = 0.f;  // row0, gates i,f,g,o
    float a01 = 0.f, a11 = 0.f, a21 = 0.f, a31 = 0.f;  // row1
    {
      const uint4 xq0 = *(const uint4*)&xc[cb][t][0][j * 4];
      const uint4 xq1 = *(const uint4*)&xc[cb][t][1][j * 4];
      const u32 e0[4] = {xq0.x, xq0.y, xq0.z, xq0.w};
      const u32 e1[4] = {xq1.x, xq1.y, xq1.z, xq1.w};
#pragma unroll
      for (int u = 0; u < 4; ++u) {
        dot2(a00, e0[u], wr[0][u]); dot2(a01, e1[u], wr[0][u]);
        dot2(a10, e0[u], wr[1][u]); dot2(a11, e1[u], wr[1][u]);
        dot2(a20, e0[u], wr[2][u]); dot2(a21, e1[u], wr[2][u]);
        dot2(a30, e0[u], wr[3][u]); dot2(a31, e1[u], wr[3][u]);
      }
      const uint4* h0 = (const uint4*)&hxh[p][0][0];
      const uint4* h1 = (const uint4*)&hxh[p][1][0];
#pragma unroll
      for (int q = 0; q < 4; ++q) {
        const uint4 hv0 = h0[4 * j + q];
        const uint4 hv1 = h1[4 * j + q];
        const u32 f0[4] = {hv0.x, hv0.y, hv0.z, hv0.w};
        const u32 f1[4] = {hv1.x, hv1.y, hv1.z, hv1.w};
#pragma unroll
        for (int u = 0; u < 4; ++u) {
          dot2(a00, f0[u], wr[0][4 + 4 * q + u]);
          dot2(a01, f1[u], wr[0][4 + 4 * q + u]);
          dot2(a10, f0[u], wr[1][4 + 4 * q + u]);
          dot2(a11, f1[u], wr[1][4 + 4 * q + u]);
          dot2(a20, f0[u], wr[2][4 + 4 * q + u]);
          dot2(a21, f1[u], wr[2][4 + 4 * q + u]);
          dot2(a30, f0[u], wr[3][4 + 4 * q + u]);
          dot2(a31, f1[u], wr[3][4 + 4 * q + u]);
        }
      }
    }
    // ---- quad butterfly reduce (VALU DPP; all 4 lanes end with the total) ----
#define QRED(v) { float t_ = (v); t_ += dpp_qp<0xB1>(t_); t_ += dpp_qp<0x4E>(t_); (v) = t_; }
    QRED(a00) QRED(a10) QRED(a20) QRED(a30)
    QRED(a01) QRED(a11) QRED(a21) QRED(a31)
#undef QRED

    // ---- activations, both rows, all lanes (branch-free, quad-redundant) ----
    const float wl = wc[cb][t * H + g];
    {
      const float gi = sigm(a00 + bias[0]);
      const float gf = sigm(a10 + bias[1]);
      const float gg = tanh_(a20 + bias[2]);
      const float go = sigm(a30 + bias[3]);
      cc0 = gf * cc0 + gi * gg;
      const float h = go * tanh_(cc0);
      if (j == 0) hxh[np][0][g] = (_Float16)h;
      oa0 += h * wl;
    }
    {
      const float gi = sigm(a01 + bias[0]);
      const float gf = sigm(a11 + bias[1]);
      const float gg = tanh_(a21 + bias[2]);
      const float go = sigm(a31 + bias[3]);
      cc1 = gf * cc1 + gi * gg;
      const float h = go * tanh_(cc1);
      if (j == 1) hxh[np][1][g] = (_Float16)h;
      oa1 += h * wl;
    }
    __syncthreads();  // the ONLY barrier per step
  }

  // ---- final reduce of fused linear ----
  if (j == 0) { redf[0][g] = oa0; redf[1][g] = oa1; }
  __syncthreads();
  if (tid < 2) {
    float sum = blin[0];
    for (int k = 0; k < H; ++k) sum += redf[tid][k];
    out[r0 + tid] = sum;
  }
}

extern "C" void kernel_launch(void* const* d_in, const int* in_sizes, int n_in,
                              void* d_out, int out_size, void* d_ws, size_t ws_size,
                              hipStream_t stream) {
  const float* x    = (const float*)d_in[0];
  const float* Wih  = (const float*)d_in[1];
  const float* Whh  = (const float*)d_in[2];
  const float* bih  = (const float*)d_in[3];
  const float* bhh  = (const float*)d_in[4];
  const float* Wlin = (const float*)d_in[5];
  const float* blin = (const float*)d_in[6];
  float* outp = (float*)d_out;
  hipLaunchKernelGGL(lstm_fused, dim3(B / 2), dim3(512), 0, stream,
                     x, Wih, Whh, bih, bhh, Wlin, blin, outp);
}